// Round 6
// baseline (957.924 us; speedup 1.0000x reference)
//
#include <hip/hip_runtime.h>
#include <hip/hip_fp16.h>

#define NLEV 20
#define TSIZE (1u << 19)
#define TMASK (TSIZE - 1u)
#define PRIME_Y 2654435761u
#define PRIME_Z 805459861u

typedef float f32x2 __attribute__((ext_vector_type(2)));
typedef float f32x4 __attribute__((ext_vector_type(4)));

// int(16 * 1.39**i) for i in 0..19 — verified, none near an integer boundary.
__device__ __constant__ int kRes[NLEV] = {
    16, 22, 30, 42, 59, 83, 115, 160, 222, 309,
    430, 598, 832, 1156, 1608, 2235, 3107, 4318, 6003, 8344};

// R3/R5-proven gather path. Hash x-adjacency: corners (v0, v0+1) with the
// same y,z hash to i0 = v0^H and i1 = (v0+1)^H. For even v0, i1 == i0^1, so
// one aligned 16-B load fetches both corners (4 lines/task). Odd v0: 8
// separate 8-B loads (8 lines/task). Avg 6 lines/task — minimal for this
// hash (only the x axis is XOR-structured).
__device__ __forceinline__ float2 encode_one(const float2* __restrict__ tbl,
                                             float r, float px, float py,
                                             float pz) {
  const float xs0 = px * r, xs1 = py * r, xs2 = pz * r;
  const float f0 = floorf(xs0), f1 = floorf(xs1), f2 = floorf(xs2);
  const float wx = xs0 - f0, wy = xs1 - f1, wz = xs2 - f2;
  const unsigned v0 = (unsigned)(int)f0;
  const unsigned v1 = (unsigned)(int)f1;
  const unsigned v2 = (unsigned)(int)f2;

  const unsigned hy0 = v1 * PRIME_Y, hy1 = (v1 + 1u) * PRIME_Y;
  const unsigned hz0 = v2 * PRIME_Z, hz1 = (v2 + 1u) * PRIME_Z;
  unsigned H[4];
  H[0] = hy0 ^ hz0;
  H[1] = hy0 ^ hz1;
  H[2] = hy1 ^ hz0;
  H[3] = hy1 ^ hz1;

  float2 e0[4], e1[4];

  if ((v0 & 1u) == 0u) {
#pragma unroll
    for (int j = 0; j < 4; ++j) {
      const unsigned i0 = (v0 ^ H[j]) & TMASK;
      const f32x4 q = *(const f32x4*)((const float*)tbl + 2u * (i0 & ~1u));
      const bool lo = (i0 & 1u) == 0u;
      e0[j] = lo ? make_float2(q.x, q.y) : make_float2(q.z, q.w);
      e1[j] = lo ? make_float2(q.z, q.w) : make_float2(q.x, q.y);
    }
  } else {
#pragma unroll
    for (int j = 0; j < 4; ++j) {
      e0[j] = tbl[(v0 ^ H[j]) & TMASK];
      e1[j] = tbl[((v0 + 1u) ^ H[j]) & TMASK];
    }
  }

  const float owx = 1.0f - wx, owy = 1.0f - wy, owz = 1.0f - wz;

  const float c00a = e0[0].x * owx + e1[0].x * wx;
  const float c01a = e0[1].x * owx + e1[1].x * wx;
  const float c10a = e0[2].x * owx + e1[2].x * wx;
  const float c11a = e0[3].x * owx + e1[3].x * wx;
  const float c0a = c00a * owy + c10a * wy;
  const float c1a = c01a * owy + c11a * wy;

  const float c00b = e0[0].y * owx + e1[0].y * wx;
  const float c01b = e0[1].y * owx + e1[1].y * wx;
  const float c10b = e0[2].y * owx + e1[2].y * wx;
  const float c11b = e0[3].y * owx + e1[3].y * wx;
  const float c0b = c00b * owy + c10b * wy;
  const float c1b = c01b * owy + c11b * wy;

  return make_float2(c0a * owz + c1a * wz, c0b * owz + c1b * wz);
}

// Kernel 1 (levels 0-9 only now): one (point, level) per thread, level-major
// dispatch; each XCD's 4 MB L2 holds ~one level's 4 MB table. All streaming
// accesses NT (R4 lesson: anything normal-cached evicts the table).
// fp16 ws halves store traffic (R5-verified).
__global__ __launch_bounds__(256) void enc_level_kernel(
    const float* __restrict__ x, const float* __restrict__ tables,
    unsigned* __restrict__ ws16, int n) {
  const int l = blockIdx.y;  // 0..9
  const int p = blockIdx.x * 256 + threadIdx.x;
  if (p >= n) return;
  const float px = __builtin_nontemporal_load(x + 3 * p + 0);
  const float py = __builtin_nontemporal_load(x + 3 * p + 1);
  const float pz = __builtin_nontemporal_load(x + 3 * p + 2);
  const float2* __restrict__ tbl = (const float2*)tables + (size_t)l * TSIZE;
  const float2 v = encode_one(tbl, (float)kRes[l], px, py, pz);
  const __half2 h = __floats2half2_rn(v.x, v.y);
  __builtin_nontemporal_store(*(const unsigned*)&h, ws16 + (size_t)l * n + p);
}

// Kernel 2 (NEW): levels 10-19 fused per-thread, writing out[p][20..40)
// directly — no ws round-trip, no transpose for the expensive fine half.
// The 10 fine tables (40 MB) exceed per-XCD L2, so gathers run in the L3
// (Infinity Cache) regime — this dispatch's duration measures L3 random
// throughput. x is read once per point for all 10 levels. Output is 80 B
// contiguous per point (5x float4 NT stores), f32 precision (no fp16 step).
__global__ __launch_bounds__(256) void fused_fine_kernel(
    const float* __restrict__ x, const float* __restrict__ tables,
    float* __restrict__ out, int n) {
  const int p = blockIdx.x * 256 + threadIdx.x;
  if (p >= n) return;
  const float px = __builtin_nontemporal_load(x + 3 * p + 0);
  const float py = __builtin_nontemporal_load(x + 3 * p + 1);
  const float pz = __builtin_nontemporal_load(x + 3 * p + 2);

  float o[20];
#pragma unroll
  for (int li = 0; li < 10; ++li) {
    const int l = 10 + li;
    const float2* __restrict__ tbl = (const float2*)tables + (size_t)l * TSIZE;
    const float2 v = encode_one(tbl, (float)kRes[l], px, py, pz);
    o[2 * li + 0] = v.x;
    o[2 * li + 1] = v.y;
  }

  float* __restrict__ dstf = out + (size_t)p * (NLEV * 2) + 20;  // 16-B aligned
#pragma unroll
  for (int k = 0; k < 5; ++k) {
    f32x4 v;
    v.x = o[4 * k + 0];
    v.y = o[4 * k + 1];
    v.z = o[4 * k + 2];
    v.w = o[4 * k + 3];
    __builtin_nontemporal_store(v, (f32x4*)(dstf + 4 * k));
  }
}

// Kernel 3: transpose ws16 (10, N) half2 -> out (N, 0..20) f32 via LDS tile
// of 128 points. LDS u32 [128][11] = 5.6 KB (stride 11, coprime with 32 ->
// conflict-free).
__global__ __launch_bounds__(256) void transpose_kernel(
    const unsigned* __restrict__ ws16, float* __restrict__ out, int n) {
  __shared__ unsigned lds[128 * 11];
  const int p0 = blockIdx.x * 128;
  const int t = threadIdx.x;
  const int npts = min(128, n - p0);

  // Phase 1: 10 levels x 128 pts = 1280 u32 -> 5 per thread (coalesced).
#pragma unroll
  for (int k = 0; k < 5; ++k) {
    const int g = t + k * 256;  // g = l*128 + pl
    const int l = g >> 7;
    const int pl = g & 127;
    if (pl < npts) {
      lds[pl * 11 + l] =
          __builtin_nontemporal_load(ws16 + (size_t)l * n + p0 + pl);
    }
  }
  __syncthreads();

  // Phase 2: 128 pts x 5 float4 (floats 0..19 of each row) -> per thread.
  f32x4* __restrict__ dst = (f32x4*)(out + (size_t)p0 * (NLEV * 2));
#pragma unroll
  for (int k = 0; k < 3; ++k) {
    const int g = t + k * 256;
    const int pl = g / 5;
    const int comp = g - pl * 5;
    if (g < npts * 5) {
      const unsigned u0 = lds[pl * 11 + comp * 2 + 0];
      const unsigned u1 = lds[pl * 11 + comp * 2 + 1];
      const float2 a = __half22float2(*(const __half2*)&u0);
      const float2 b = __half22float2(*(const __half2*)&u1);
      f32x4 v;
      v.x = a.x;
      v.y = a.y;
      v.z = b.x;
      v.w = b.y;
      __builtin_nontemporal_store(v, dst + pl * 10 + comp);
    }
  }
}

// Fallback: direct per-point, all levels, used only if ws too small.
__global__ __launch_bounds__(256) void hash_enc_kernel(
    const float* __restrict__ x, const float* __restrict__ tables,
    float* __restrict__ out, int n) {
  int p = blockIdx.x * 256 + threadIdx.x;
  if (p >= n) return;
  const float px = x[3 * p + 0];
  const float py = x[3 * p + 1];
  const float pz = x[3 * p + 2];
  float o[NLEV * 2];
#pragma unroll
  for (int l = 0; l < NLEV; ++l) {
    const float2* tbl = (const float2*)tables + (size_t)l * TSIZE;
    const float2 v = encode_one(tbl, (float)kRes[l], px, py, pz);
    o[2 * l + 0] = v.x;
    o[2 * l + 1] = v.y;
  }
  float4* __restrict__ dst = (float4*)(out + (size_t)p * (NLEV * 2));
#pragma unroll
  for (int k = 0; k < 10; ++k) {
    dst[k] = make_float4(o[4 * k + 0], o[4 * k + 1], o[4 * k + 2], o[4 * k + 3]);
  }
}

extern "C" void kernel_launch(void* const* d_in, const int* in_sizes, int n_in,
                              void* d_out, int out_size, void* d_ws, size_t ws_size,
                              hipStream_t stream) {
  const float* x = (const float*)d_in[0];       // (N, 3) f32
  const float* tables = (const float*)d_in[1];  // (20, 2^19, 2) f32
  float* out = (float*)d_out;                   // (N, 40) f32
  const int n = in_sizes[0] / 3;
  const size_t ws_needed = (size_t)10 * n * sizeof(unsigned);  // fp16 ws, 10 lv

  if (ws_size >= ws_needed) {
    const int pblocks = (n + 255) / 256;
    dim3 grid1(pblocks, 10);
    enc_level_kernel<<<grid1, 256, 0, stream>>>(x, tables, (unsigned*)d_ws, n);
    fused_fine_kernel<<<pblocks, 256, 0, stream>>>(x, tables, out, n);
    const int tblocks = (n + 127) / 128;
    transpose_kernel<<<tblocks, 256, 0, stream>>>((const unsigned*)d_ws, out, n);
  } else {
    const int grid = (n + 255) / 256;
    hash_enc_kernel<<<grid, 256, 0, stream>>>(x, tables, out, n);
  }
}